// Round 6
// baseline (235.525 us; speedup 1.0000x reference)
//
#include <hip/hip_runtime.h>

// TELIF: temporal-encoding LIF neuron scan.
// tx: [T,B,N] fp32, TE: [N,T] fp32, out: [T,B,N] fp32. T=512,B=64,N=1024.
//
// R5 post-mortem: R1/R2/R5 (three pipeline depths) all ~62us kernel ->
// scheduling depth exhausted; remaining gap vs copy-kernel byte rate is
// VMEM instruction economics (scalar dword per lane). R6: each thread runs
// TWO adjacent (b,n) LIF chains -> dwordx2 tx/out (512B per wave-instr),
// half the VMEM instrs per byte. 32768 threads in 64-thread blocks
// (512 blocks = 2 waves/CU); quad-buffer + sched_barrier pins kept from R5.

#define T_STEPS 512
#define BN      (64 * 1024)

typedef float v2f __attribute__((ext_vector_type(2)));
typedef float v4f __attribute__((ext_vector_type(4)));

#define NTL2(i) __builtin_nontemporal_load(reinterpret_cast<const v2f*>(txp + (size_t)(i) * BN))
#define LDA(i)  (*reinterpret_cast<const v4f*>(tep0 + (i)))
#define LDB(i)  (*reinterpret_cast<const v4f*>(tep1 + (i)))

// Chunk storage: 16 v2f (tx, 2 elems x 16 steps) + 8 v4f (TE rows n, n+1).
#define DECLC(r, s) \
  v2f r##00, r##01, r##02, r##03, r##04, r##05, r##06, r##07, \
      r##08, r##09, r##10, r##11, r##12, r##13, r##14, r##15; \
  v4f s##0, s##1, s##2, s##3, s##4, s##5, s##6, s##7;

// Prefetch 16 steps of tx for both elements (dwordx2 each).
#define PFX(r, base) \
  r##00 = NTL2((base)+0);  r##01 = NTL2((base)+1);  r##02 = NTL2((base)+2);  r##03 = NTL2((base)+3);  \
  r##04 = NTL2((base)+4);  r##05 = NTL2((base)+5);  r##06 = NTL2((base)+6);  r##07 = NTL2((base)+7);  \
  r##08 = NTL2((base)+8);  r##09 = NTL2((base)+9);  r##10 = NTL2((base)+10); r##11 = NTL2((base)+11); \
  r##12 = NTL2((base)+12); r##13 = NTL2((base)+13); r##14 = NTL2((base)+14); r##15 = NTL2((base)+15);

// Prefetch 16 steps of TE for rows n (s0..s3) and n+1 (s4..s7).
#define PFE(s, base) \
  s##0 = LDA((base));    s##1 = LDA((base)+4);  s##2 = LDA((base)+8);  s##3 = LDA((base)+12); \
  s##4 = LDB((base));    s##5 = LDB((base)+4);  s##6 = LDB((base)+8);  s##7 = LDB((base)+12);

// One LIF step for BOTH chains, exact reference op order (fp contract off):
//   th = th + v*te - (th-THRESHOLD)*BETA ; v = v*DECAY*(1-y) + x ; y = (v>th)
#define STEP2(xv, t0v, t1v, tt) { \
  float A0_ = v0 * (t0v); float B0_ = th0 + A0_; float C0_ = th0 - 0.3f; \
  float D0_ = C0_ * 0.02f; th0 = B0_ - D0_; \
  float E0_ = v0 * 0.2f; float F0_ = 1.0f - y0; float G0_ = E0_ * F0_; \
  v0 = G0_ + (xv).x; y0 = (v0 > th0) ? 1.0f : 0.0f; \
  float A1_ = v1 * (t1v); float B1_ = th1 + A1_; float C1_ = th1 - 0.3f; \
  float D1_ = C1_ * 0.02f; th1 = B1_ - D1_; \
  float E1_ = v1 * 0.2f; float F1_ = 1.0f - y1; float G1_ = E1_ * F1_; \
  v1 = G1_ + (xv).y; y1 = (v1 > th1) ? 1.0f : 0.0f; \
  v2f Y_; Y_.x = y0; Y_.y = y1; \
  __builtin_nontemporal_store(Y_, reinterpret_cast<v2f*>(outp + (size_t)(tt) * BN)); }

#define COMP(r, s, base) \
  STEP2(r##00, s##0 .x, s##4 .x, (base)+0)  STEP2(r##01, s##0 .y, s##4 .y, (base)+1)  \
  STEP2(r##02, s##0 .z, s##4 .z, (base)+2)  STEP2(r##03, s##0 .w, s##4 .w, (base)+3)  \
  STEP2(r##04, s##1 .x, s##5 .x, (base)+4)  STEP2(r##05, s##1 .y, s##5 .y, (base)+5)  \
  STEP2(r##06, s##1 .z, s##5 .z, (base)+6)  STEP2(r##07, s##1 .w, s##5 .w, (base)+7)  \
  STEP2(r##08, s##2 .x, s##6 .x, (base)+8)  STEP2(r##09, s##2 .y, s##6 .y, (base)+9)  \
  STEP2(r##10, s##2 .z, s##6 .z, (base)+10) STEP2(r##11, s##2 .w, s##6 .w, (base)+11) \
  STEP2(r##12, s##3 .x, s##7 .x, (base)+12) STEP2(r##13, s##3 .y, s##7 .y, (base)+13) \
  STEP2(r##14, s##3 .z, s##7 .z, (base)+14) STEP2(r##15, s##3 .w, s##7 .w, (base)+15)

#define PIN() __builtin_amdgcn_sched_barrier(0)

__global__ __launch_bounds__(64, 1) void telif_kernel(
    const float* __restrict__ tx, const float* __restrict__ TE,
    float* __restrict__ out)
{
#pragma clang fp contract(off)

    const int gid   = blockIdx.x * 64 + threadIdx.x;
    const int flat2 = gid * 2;              // even: both elems share b, rows n, n+1
    const int n     = flat2 & 1023;

    const float* txp  = tx + flat2;         // dwordx2/lane, 512 B/wave-instr
    const float* tep0 = TE + n * T_STEPS;   // row n, contiguous over t
    const float* tep1 = tep0 + T_STEPS;     // row n+1
    float*       outp = out + flat2;

    float v0 = 0.0f, y0 = 0.0f, th0 = 0.3f;
    float v1 = 0.0f, y1 = 0.0f, th1 = 0.3f;

    // Quad buffer: chunks A/B/C/D of 16 steps each; 32-step lookahead.
    DECLC(a, e) DECLC(b, f) DECLC(c, g) DECLC(d, h)

    PFX(a, 0)  PFE(e, 0)
    PFX(b, 16) PFE(f, 16)
    PIN();

#pragma unroll 1
    for (int t = 0; t < 448; t += 64) {
        PFX(c, t + 32) PFE(g, t + 32)
        PFX(d, t + 48) PFE(h, t + 48)
        PIN();                              // loads stay ABOVE the compute
        COMP(a, e, t)
        COMP(b, f, t + 16)
        PIN();
        PFX(a, t + 64) PFE(e, t + 64)
        PFX(b, t + 80) PFE(f, t + 80)
        PIN();
        COMP(c, g, t + 32)
        COMP(d, h, t + 48)
        PIN();
    }
    // Tail: A=448, B=464 already in registers; fetch 480/496 and finish.
    PFX(c, 480) PFE(g, 480)
    PFX(d, 496) PFE(h, 496)
    PIN();
    COMP(a, e, 448)
    COMP(b, f, 464)
    COMP(c, g, 480)
    COMP(d, h, 496)
}

extern "C" void kernel_launch(void* const* d_in, const int* in_sizes, int n_in,
                              void* d_out, int out_size, void* d_ws, size_t ws_size,
                              hipStream_t stream) {
    const float* tx = (const float*)d_in[0];  // [T, B, N]
    const float* TE = (const float*)d_in[1];  // [N, T]
    float* out = (float*)d_out;               // [T, B, N]
    telif_kernel<<<512, 64, 0, stream>>>(tx, TE, out);
}